// Round 1
// baseline (18.976 us; speedup 1.0000x reference)
//
#include <hip/hip_runtime.h>
#include <math.h>

#define MM 8192
#define NN 64
#define NB 25
#define WAVES 4

struct Q { float w, x, y, z; };

__device__ __forceinline__ Q qmul(const Q a, const Q b) {
    Q r;
    r.w = a.w*b.w - a.x*b.x - a.y*b.y - a.z*b.z;
    r.x = a.w*b.x + b.w*a.x + a.y*b.z - a.z*b.y;
    r.y = a.w*b.y + b.w*a.y + a.z*b.x - a.x*b.z;
    r.z = a.w*b.z + b.w*a.z + a.x*b.y - a.y*b.x;
    return r;
}

__global__ __launch_bounds__(WAVES*64) void skin_kernel(
    const float* __restrict__ xyz,
    const float* __restrict__ t_qr,
    const float* __restrict__ t_qd,
    const float* __restrict__ rest_qr,
    const float* __restrict__ rest_qd,
    const float* __restrict__ log_gauss,
    float* __restrict__ out)
{
    // per-wave bone data; inner-loop reads are wave-uniform (broadcast, no bank conflicts)
    __shared__ float s_mat[WAVES][NB][12];  // inv-scaled rows of R(qconj(rest_qr)) + inv-scaled translation
    __shared__ float s_qr[WAVES][NB][4];    // sign-fixed se3 real part
    __shared__ float s_qd[WAVES][NB][4];    // sign-fixed se3 dual part
    __shared__ float s_is[NB][3];           // exp(-log_gauss) = 1/scale

    const int wave = threadIdx.x >> 6;
    const int lane = threadIdx.x & 63;
    const int m = blockIdx.x * WAVES + wave;

    if (threadIdx.x < NB * 3) {
        s_is[threadIdx.x / 3][threadIdx.x % 3] = __expf(-log_gauss[threadIdx.x]);
    }
    __syncthreads();

    if (lane < NB) {
        const int base = (m * NB + lane) * 4;
        const float4 Tqv = *reinterpret_cast<const float4*>(t_qr + base);
        const float4 Tdv = *reinterpret_cast<const float4*>(t_qd + base);
        const float4 Rqv = *reinterpret_cast<const float4*>(rest_qr + base);
        const float4 Rdv = *reinterpret_cast<const float4*>(rest_qd + base);
        const Q Tq{Tqv.x, Tqv.y, Tqv.z, Tqv.w};
        const Q Td{Tdv.x, Tdv.y, Tdv.z, Tdv.w};
        const Q Rq{Rqv.x, Rqv.y, Rqv.z, Rqv.w};
        const Q Rd{Rdv.x, Rdv.y, Rdv.z, Rdv.w};
        const Q Rqc{Rq.w, -Rq.x, -Rq.y, -Rq.z};
        const Q Rdc{Rd.w, -Rd.x, -Rd.y, -Rd.z};

        // se3 = t_art * inverse(rest_art)
        const Q se_r = qmul(Tq, Rqc);
        const Q m1 = qmul(Tq, Rdc);
        const Q m2 = qmul(Td, Rqc);
        const Q se_d{m1.w + m2.w, m1.x + m2.x, m1.y + m2.y, m1.z + m2.z};

        // hemisphere sign vs bone 0 (sign(0) -> 1)
        const float d0 = se_r.w * __shfl(se_r.w, 0)
                       + se_r.x * __shfl(se_r.x, 0)
                       + se_r.y * __shfl(se_r.y, 0)
                       + se_r.z * __shfl(se_r.z, 0);
        const float sg = (d0 < 0.f) ? -1.f : 1.f;

        s_qr[wave][lane][0] = sg * se_r.w;
        s_qr[wave][lane][1] = sg * se_r.x;
        s_qr[wave][lane][2] = sg * se_r.y;
        s_qr[wave][lane][3] = sg * se_r.z;
        s_qd[wave][lane][0] = sg * se_d.w;
        s_qd[wave][lane][1] = sg * se_d.x;
        s_qd[wave][lane][2] = sg * se_d.y;
        s_qd[wave][lane][3] = sg * se_d.z;

        // bone-inverse transform: rot = qconj(rest_qr), trans = 2*qmul(qconj(rest_qd), rest_qr).vec
        const Q tq = qmul(Rdc, Rq);
        const float tbx = 2.f * tq.x, tby = 2.f * tq.y, tbz = 2.f * tq.z;

        // rotation matrix of the (unit) quaternion Rqc, rows pre-scaled by 1/scale
        const float qw = Rqc.w, qx = Rqc.x, qy = Rqc.y, qz = Rqc.z;
        const float r00 = 1.f - 2.f*(qy*qy + qz*qz), r01 = 2.f*(qx*qy - qw*qz), r02 = 2.f*(qx*qz + qw*qy);
        const float r10 = 2.f*(qx*qy + qw*qz), r11 = 1.f - 2.f*(qx*qx + qz*qz), r12 = 2.f*(qy*qz - qw*qx);
        const float r20 = 2.f*(qx*qz - qw*qy), r21 = 2.f*(qy*qz + qw*qx), r22 = 1.f - 2.f*(qx*qx + qy*qy);
        const float i0 = s_is[lane][0], i1 = s_is[lane][1], i2 = s_is[lane][2];
        float* mp = s_mat[wave][lane];
        mp[0] = r00*i0; mp[1]  = r01*i0; mp[2]  = r02*i0; mp[3]  = tbx*i0;
        mp[4] = r10*i1; mp[5]  = r11*i1; mp[6]  = r12*i1; mp[7]  = tby*i1;
        mp[8] = r20*i2; mp[9]  = r21*i2; mp[10] = r22*i2; mp[11] = tbz*i2;
    }
    __syncthreads();

    // one point per lane (N*D == 64)
    const int pbase = (m * NN + lane) * 3;
    const float px = xyz[pbase], py = xyz[pbase + 1], pz = xyz[pbase + 2];

    float logit[NB];
    float mx = -1e30f;
#pragma unroll
    for (int b = 0; b < NB; ++b) {
        const float* mp = s_mat[wave][b];
        const float vx = fmaf(mp[0], px, fmaf(mp[1],  py, fmaf(mp[2],  pz, mp[3])));
        const float vy = fmaf(mp[4], px, fmaf(mp[5],  py, fmaf(mp[6],  pz, mp[7])));
        const float vz = fmaf(mp[8], px, fmaf(mp[9],  py, fmaf(mp[10], pz, mp[11])));
        const float lg = -0.5f * (vx*vx + vy*vy + vz*vz);
        logit[b] = lg;
        mx = fmaxf(mx, lg);
    }

    // blend with unnormalized weights: softmax denominator cancels in qr/|qr| and qd/|qr|
    float aw = 0.f, ax = 0.f, ay = 0.f, az = 0.f;
    float bw = 0.f, bx = 0.f, by = 0.f, bz = 0.f;
#pragma unroll
    for (int b = 0; b < NB; ++b) {
        const float e = __expf(logit[b] - mx);
        aw = fmaf(e, s_qr[wave][b][0], aw);
        ax = fmaf(e, s_qr[wave][b][1], ax);
        ay = fmaf(e, s_qr[wave][b][2], ay);
        az = fmaf(e, s_qr[wave][b][3], az);
        bw = fmaf(e, s_qd[wave][b][0], bw);
        bx = fmaf(e, s_qd[wave][b][1], bx);
        by = fmaf(e, s_qd[wave][b][2], by);
        bz = fmaf(e, s_qd[wave][b][3], bz);
    }

    const float inv = rsqrtf(aw*aw + ax*ax + ay*ay + az*az);
    const Q qr{aw*inv, ax*inv, ay*inv, az*inv};
    const Q qd{bw*inv, bx*inv, by*inv, bz*inv};
    const Q qrc{qr.w, -qr.x, -qr.y, -qr.z};
    const Q tq = qmul(qd, qrc);

    // rotate p by qr (reference qrotate form) + 2*dual translation
    const float uvx = qr.y*pz - qr.z*py;
    const float uvy = qr.z*px - qr.x*pz;
    const float uvz = qr.x*py - qr.y*px;
    const float cx = qr.y*uvz - qr.z*uvy;
    const float cy = qr.z*uvx - qr.x*uvz;
    const float cz = qr.x*uvy - qr.y*uvx;

    out[pbase]     = px + 2.f*(qr.w*uvx + cx) + 2.f*tq.x;
    out[pbase + 1] = py + 2.f*(qr.w*uvy + cy) + 2.f*tq.y;
    out[pbase + 2] = pz + 2.f*(qr.w*uvz + cz) + 2.f*tq.z;
}

extern "C" void kernel_launch(void* const* d_in, const int* in_sizes, int n_in,
                              void* d_out, int out_size, void* d_ws, size_t ws_size,
                              hipStream_t stream) {
    const float* xyz      = (const float*)d_in[0];
    const float* t_qr     = (const float*)d_in[1];
    const float* t_qd     = (const float*)d_in[2];
    const float* rest_qr  = (const float*)d_in[3];
    const float* rest_qd  = (const float*)d_in[4];
    const float* log_gauss= (const float*)d_in[5];
    float* out = (float*)d_out;

    dim3 grid(MM / WAVES);
    dim3 block(WAVES * 64);
    hipLaunchKernelGGL(skin_kernel, grid, block, 0, stream,
                       xyz, t_qr, t_qd, rest_qr, rest_qd, log_gauss, out);
}